// Round 1
// baseline (303.752 us; speedup 1.0000x reference)
//
#include <hip/hip_runtime.h>
#include <stdint.h>

#define TOKENS 8192
#define INF    4096
#define OUTF   4096
#define RANK   256

typedef __attribute__((ext_vector_type(8))) short bf16x8;
typedef __attribute__((ext_vector_type(4))) float f32x4;

__device__ __forceinline__ unsigned short f2bf(float f) {
    union { float f; unsigned int u; } v; v.f = f;
    unsigned int r = v.u + 0x7FFFu + ((v.u >> 16) & 1u);   // RNE
    return (unsigned short)(r >> 16);
}

__device__ __forceinline__ void gl_lds16(const void* g, void* l) {
    __builtin_amdgcn_global_load_lds(
        (const __attribute__((address_space(1))) unsigned int*)g,
        (__attribute__((address_space(3))) unsigned int*)l, 16, 0, 0);
}

// ---------------- fp32 -> bf16 convert (V, U) ----------------
__global__ void cvt4(const float4* __restrict__ in, ushort4* __restrict__ out) {
    int i = blockIdx.x * blockDim.x + threadIdx.x;
    float4 v = in[i];
    ushort4 o;
    o.x = f2bf(v.x); o.y = f2bf(v.y); o.z = f2bf(v.z); o.w = f2bf(v.w);
    out[i] = o;
}

// ---------------- GEMM1: T[8192,256] = x @ V^T (bf16 MFMA) ----------------
// BM=32, BN=256(full), BK=64, 256 thr (4 waves), grid = 256 blocks.
#define G1_BM 32
#define G1_BK 64
#define A1_STRIDE 72   // padded bf16 elems/row -> conflict-free A frag reads

__global__ __launch_bounds__(256) void gemm1(const float* __restrict__ x,
                                             const unsigned short* __restrict__ Vb,
                                             unsigned short* __restrict__ T) {
    __shared__ __align__(16) unsigned short Alds[G1_BM * A1_STRIDE]; // 4.6 KB
    __shared__ __align__(16) unsigned short Blds[RANK * G1_BK];      // 32 KB

    const int tid  = threadIdx.x;
    const int lane = tid & 63;
    const int wid  = tid >> 6;           // 0..3
    const int m0   = blockIdx.x * G1_BM;
    const int l15  = lane & 15;
    const int quad = lane >> 4;

    // A staging: thread -> (row 0..31, 8-elem segment 0..7)
    const int arow = tid >> 3;
    const int aseg = tid & 7;
    const float* xa = x + (size_t)(m0 + arow) * INF + aseg * 8;
    unsigned short* alds_w = &Alds[arow * A1_STRIDE + aseg * 8];

    // B staging lane decomposition (8 rows x 8 chunks per instr), XOR swizzle
    const int b_lrow = lane >> 3;
    const int b_cf   = (lane & 7) ^ b_lrow;   // fetch chunk = pos ^ (row&7)

    f32x4 acc[2][4];
    #pragma unroll
    for (int i = 0; i < 2; i++)
        #pragma unroll
        for (int j = 0; j < 4; j++) acc[i][j] = (f32x4){0.f, 0.f, 0.f, 0.f};

    for (int kk = 0; kk < INF; kk += G1_BK) {
        // stage B (V bf16) via async global->LDS, swizzled
        #pragma unroll
        for (int j = 0; j < 8; ++j) {
            int r0 = wid * 64 + j * 8;
            gl_lds16(Vb + (size_t)(r0 + b_lrow) * INF + kk + b_cf * 8,
                     &Blds[r0 * G1_BK]);
        }
        // stage A (x fp32 -> bf16) via regular loads + ds_write_b128
        float4 va = *(const float4*)(xa + kk);
        float4 vb = *(const float4*)(xa + kk + 4);
        {
            union { bf16x8 v; unsigned short s[8]; } pk;
            pk.s[0] = f2bf(va.x); pk.s[1] = f2bf(va.y);
            pk.s[2] = f2bf(va.z); pk.s[3] = f2bf(va.w);
            pk.s[4] = f2bf(vb.x); pk.s[5] = f2bf(vb.y);
            pk.s[6] = f2bf(vb.z); pk.s[7] = f2bf(vb.w);
            *(bf16x8*)alds_w = pk.v;
        }
        __syncthreads();
        #pragma unroll
        for (int ks = 0; ks < 2; ++ks) {
            bf16x8 af[2], bfr[4];
            #pragma unroll
            for (int mt = 0; mt < 2; ++mt) {
                int row = mt * 16 + l15;
                af[mt] = *(const bf16x8*)&Alds[row * A1_STRIDE + ks * 32 + quad * 8];
            }
            #pragma unroll
            for (int nt = 0; nt < 4; ++nt) {
                int n   = wid * 64 + nt * 16 + l15;
                int pos = (ks * 4 + quad) ^ (l15 & 7);
                bfr[nt] = *(const bf16x8*)&Blds[n * G1_BK + pos * 8];
            }
            #pragma unroll
            for (int mt = 0; mt < 2; ++mt)
                #pragma unroll
                for (int nt = 0; nt < 4; ++nt)
                    acc[mt][nt] = __builtin_amdgcn_mfma_f32_16x16x32_bf16(
                        af[mt], bfr[nt], acc[mt][nt], 0, 0, 0);
        }
        __syncthreads();
    }
    // epilogue: T bf16, C/D layout col=lane&15, row=quad*4+r
    #pragma unroll
    for (int mt = 0; mt < 2; ++mt)
        #pragma unroll
        for (int nt = 0; nt < 4; ++nt) {
            int col = wid * 64 + nt * 16 + l15;
            #pragma unroll
            for (int r = 0; r < 4; ++r) {
                int row = m0 + mt * 16 + quad * 4 + r;
                T[(size_t)row * RANK + col] = f2bf(acc[mt][nt][r]);
            }
        }
}

// ---------------- GEMM2: out = T @ U^T + bias (bf16 MFMA, fp32 out) -------
// BM=128, BN=128, BK=64, K=256 (4 iters), 256 thr, grid = 32 x 64.
#define G2_BM 128
#define G2_BN 128
#define G2_BK 64

__global__ __launch_bounds__(256) void gemm2(const unsigned short* __restrict__ Tb,
                                             const unsigned short* __restrict__ Ub,
                                             const float* __restrict__ bias,
                                             float* __restrict__ out) {
    __shared__ __align__(16) unsigned short Alds[G2_BM * G2_BK]; // 16 KB
    __shared__ __align__(16) unsigned short Blds[G2_BN * G2_BK]; // 16 KB

    const int tid  = threadIdx.x;
    const int lane = tid & 63;
    const int wid  = tid >> 6;
    const int wy   = wid >> 1, wx = wid & 1;
    const int m0   = blockIdx.y * G2_BM;
    const int n0   = blockIdx.x * G2_BN;
    const int l15  = lane & 15, quad = lane >> 4;
    const int lrow = lane >> 3;
    const int cf   = (lane & 7) ^ lrow;

    f32x4 acc[4][4];
    #pragma unroll
    for (int i = 0; i < 4; i++)
        #pragma unroll
        for (int j = 0; j < 4; j++) acc[i][j] = (f32x4){0.f, 0.f, 0.f, 0.f};

    for (int kk = 0; kk < RANK; kk += G2_BK) {
        #pragma unroll
        for (int j = 0; j < 4; ++j) {
            int r0 = wid * 32 + j * 8;
            gl_lds16(Tb + (size_t)(m0 + r0 + lrow) * RANK + kk + cf * 8,
                     &Alds[r0 * G2_BK]);
            gl_lds16(Ub + (size_t)(n0 + r0 + lrow) * RANK + kk + cf * 8,
                     &Blds[r0 * G2_BK]);
        }
        __syncthreads();
        #pragma unroll
        for (int ks = 0; ks < 2; ++ks) {
            bf16x8 af[4], bfr[4];
            #pragma unroll
            for (int t = 0; t < 4; ++t) {
                int ar = wy * 64 + t * 16 + l15;
                int ap = (ks * 4 + quad) ^ (ar & 7);
                af[t] = *(const bf16x8*)&Alds[ar * G2_BK + ap * 8];
                int br = wx * 64 + t * 16 + l15;
                int bp = (ks * 4 + quad) ^ (br & 7);
                bfr[t] = *(const bf16x8*)&Blds[br * G2_BK + bp * 8];
            }
            #pragma unroll
            for (int mt = 0; mt < 4; ++mt)
                #pragma unroll
                for (int nt = 0; nt < 4; ++nt)
                    acc[mt][nt] = __builtin_amdgcn_mfma_f32_16x16x32_bf16(
                        af[mt], bfr[nt], acc[mt][nt], 0, 0, 0);
        }
        __syncthreads();
    }
    // epilogue: + bias, fp32 stores
    float bv[4];
    #pragma unroll
    for (int nt = 0; nt < 4; ++nt) bv[nt] = bias[n0 + wx * 64 + nt * 16 + l15];
    #pragma unroll
    for (int mt = 0; mt < 4; ++mt)
        #pragma unroll
        for (int nt = 0; nt < 4; ++nt) {
            int col = n0 + wx * 64 + nt * 16 + l15;
            #pragma unroll
            for (int r = 0; r < 4; ++r) {
                int row = m0 + wy * 64 + mt * 16 + quad * 4 + r;
                out[(size_t)row * OUTF + col] = acc[mt][nt][r] + bv[nt];
            }
        }
}

extern "C" void kernel_launch(void* const* d_in, const int* in_sizes, int n_in,
                              void* d_out, int out_size, void* d_ws, size_t ws_size,
                              hipStream_t stream) {
    const float* x    = (const float*)d_in[0];
    const float* U    = (const float*)d_in[1];
    const float* V    = (const float*)d_in[2];
    const float* bias = (const float*)d_in[3];
    float* out = (float*)d_out;

    // ws layout: Vb (2MB) | Ub (2MB) | Tb (4MB)  => 8 MB total
    unsigned short* Vb = (unsigned short*)d_ws;
    unsigned short* Ub = Vb + (size_t)RANK * INF;
    unsigned short* Tb = Ub + (size_t)OUTF * RANK;

    cvt4<<<(RANK * INF / 4) / 256, 256, 0, stream>>>((const float4*)V, (ushort4*)Vb);
    cvt4<<<(OUTF * RANK / 4) / 256, 256, 0, stream>>>((const float4*)U, (ushort4*)Ub);
    gemm1<<<TOKENS / G1_BM, 256, 0, stream>>>(x, Vb, Tb);
    gemm2<<<dim3(OUTF / G2_BN, TOKENS / G2_BM), 256, 0, stream>>>(Tb, Ub, bias, out);
}

// Round 2
// 293.690 us; speedup vs baseline: 1.0343x; 1.0343x over previous
//
#include <hip/hip_runtime.h>
#include <stdint.h>

#define TOKENS 8192
#define INF    4096
#define OUTF   4096
#define RANK   256

typedef __attribute__((ext_vector_type(8))) short bf16x8;
typedef __attribute__((ext_vector_type(4))) float f32x4;

__device__ __forceinline__ unsigned short f2bf(float f) {
    union { float f; unsigned int u; } v; v.f = f;
    unsigned int r = v.u + 0x7FFFu + ((v.u >> 16) & 1u);   // RNE
    return (unsigned short)(r >> 16);
}

__device__ __forceinline__ void gl_lds16(const void* g, void* l) {
    __builtin_amdgcn_global_load_lds(
        (const __attribute__((address_space(1))) unsigned int*)g,
        (__attribute__((address_space(3))) unsigned int*)l, 16, 0, 0);
}

// ---------------- fp32 -> bf16 convert (V, U) ----------------
__global__ void cvt4(const float4* __restrict__ in, ushort4* __restrict__ out) {
    int i = blockIdx.x * blockDim.x + threadIdx.x;
    float4 v = in[i];
    ushort4 o;
    o.x = f2bf(v.x); o.y = f2bf(v.y); o.z = f2bf(v.z); o.w = f2bf(v.w);
    out[i] = o;
}

// ---------------- GEMM1: T[8192,256] = x @ V^T (bf16 MFMA) ----------------
// BM=32 tokens, BN=128 rank, BK=128. 512 thr (8 waves), grid = 2 x 256
// => 512 blocks = 2 blocks/CU, 16 waves/CU (occupancy fix vs round 1).
#define G1_BM 32
#define G1_BN 128
#define G1_BK 128
#define A1_STR 136   // padded bf16 elems/row for x-tile

__global__ __launch_bounds__(512) void gemm1(const float* __restrict__ x,
                                             const unsigned short* __restrict__ Vb,
                                             unsigned short* __restrict__ T) {
    __shared__ __align__(16) unsigned short Axlds[G1_BM * A1_STR];   // 8.5 KB
    __shared__ __align__(16) unsigned short Bvlds[G1_BN * G1_BK];    // 32 KB

    const int tid  = threadIdx.x;
    const int lane = tid & 63;
    const int wid  = tid >> 6;            // 0..7
    const int m0   = blockIdx.y * G1_BM;  // token base
    const int n0   = blockIdx.x * G1_BN;  // rank base
    const int l15  = lane & 15;
    const int quad = lane >> 4;

    // A staging: thread -> (row 0..31, 8-elem k segment 0..15)
    const int arow = tid >> 4;
    const int aseg = tid & 15;
    const float* xa = x + (size_t)(m0 + arow) * INF + aseg * 8;
    unsigned short* alds_w = &Axlds[arow * A1_STR + aseg * 8];

    // B staging: per instr 4 rows x 16 chunks, XOR-swizzled chunk
    const int b_lrow = lane >> 4;         // 0..3
    const int b_pos  = lane & 15;         // chunk position in LDS row

    f32x4 acc[2];
    acc[0] = (f32x4){0.f, 0.f, 0.f, 0.f};
    acc[1] = (f32x4){0.f, 0.f, 0.f, 0.f};

    for (int kk = 0; kk < INF; kk += G1_BK) {
        // stage B (V bf16) via async global->LDS, 4 rounds x 4 rows/wave
        #pragma unroll
        for (int j = 0; j < 4; ++j) {
            int r0  = j * 32 + wid * 4;
            int row = r0 + b_lrow;
            int cf  = b_pos ^ (row & 7);
            gl_lds16(Vb + (size_t)(n0 + row) * INF + kk + cf * 8,
                     &Bvlds[r0 * G1_BK]);
        }
        // stage A (x fp32 -> bf16): 2 float4 loads, pack, 1 ds_write_b128
        float4 va = *(const float4*)(xa + kk);
        float4 vb = *(const float4*)(xa + kk + 4);
        {
            union { bf16x8 v; unsigned short s[8]; } pk;
            pk.s[0] = f2bf(va.x); pk.s[1] = f2bf(va.y);
            pk.s[2] = f2bf(va.z); pk.s[3] = f2bf(va.w);
            pk.s[4] = f2bf(vb.x); pk.s[5] = f2bf(vb.y);
            pk.s[6] = f2bf(vb.z); pk.s[7] = f2bf(vb.w);
            *(bf16x8*)alds_w = pk.v;
        }
        __syncthreads();
        #pragma unroll
        for (int ks = 0; ks < 4; ++ks) {
            // A-operand = V fragment (rank rows): lane holds V[rr=l15][k]
            int rr = wid * 16 + l15;
            int p  = (ks * 4 + quad) ^ (rr & 7);
            bf16x8 aV = *(const bf16x8*)&Bvlds[rr * G1_BK + p * 8];
            // B-operand = x fragment (token cols): lane holds x[tr=l15][k]
            #pragma unroll
            for (int mt = 0; mt < 2; ++mt) {
                int tr = mt * 16 + l15;
                bf16x8 bx = *(const bf16x8*)&Axlds[tr * A1_STR + ks * 32 + quad * 8];
                acc[mt] = __builtin_amdgcn_mfma_f32_16x16x32_bf16(aV, bx, acc[mt], 0, 0, 0);
            }
        }
        __syncthreads();
    }
    // epilogue: D row = rank offset (quad*4+r), col = token (l15)
    // => lane's 4 regs are 4 consecutive rank cols of one T row: ushort4 store
    #pragma unroll
    for (int mt = 0; mt < 2; ++mt) {
        int m      = m0 + mt * 16 + l15;
        int n_base = n0 + wid * 16 + quad * 4;
        ushort4 o;
        o.x = f2bf(acc[mt][0]); o.y = f2bf(acc[mt][1]);
        o.z = f2bf(acc[mt][2]); o.w = f2bf(acc[mt][3]);
        *(ushort4*)&T[(size_t)m * RANK + n_base] = o;
    }
}

// ---------------- GEMM2: out = T @ U^T + bias (bf16 MFMA, fp32 out) -------
// BM=128 tokens, BN=128 outf, BK=64, K=256 (4 iters), 256 thr, grid 32x64.
// Operand-swapped: A=U-frag, B=T-frag => float4 epilogue stores.
#define G2_BM 128
#define G2_BN 128
#define G2_BK 64

__global__ __launch_bounds__(256) void gemm2(const unsigned short* __restrict__ Tb,
                                             const unsigned short* __restrict__ Ub,
                                             const float* __restrict__ bias,
                                             float* __restrict__ out) {
    __shared__ __align__(16) unsigned short Tlds[G2_BM * G2_BK]; // 16 KB
    __shared__ __align__(16) unsigned short Ulds[G2_BN * G2_BK]; // 16 KB

    const int tid  = threadIdx.x;
    const int lane = tid & 63;
    const int wid  = tid >> 6;
    const int wy   = wid >> 1, wx = wid & 1;     // token half / outf half
    const int m0   = blockIdx.y * G2_BM;
    const int n0   = blockIdx.x * G2_BN;
    const int l15  = lane & 15, quad = lane >> 4;
    const int lrow = lane >> 3;                  // 0..7 (8 rows per instr)
    const int cf   = (lane & 7) ^ lrow;          // swizzled fetch chunk

    f32x4 acc[4][4];   // [nt][mt]
    #pragma unroll
    for (int i = 0; i < 4; i++)
        #pragma unroll
        for (int j = 0; j < 4; j++) acc[i][j] = (f32x4){0.f, 0.f, 0.f, 0.f};

    for (int kk = 0; kk < RANK; kk += G2_BK) {
        #pragma unroll
        for (int j = 0; j < 4; ++j) {
            int r0 = wid * 32 + j * 8;
            gl_lds16(Tb + (size_t)(m0 + r0 + lrow) * RANK + kk + cf * 8,
                     &Tlds[r0 * G2_BK]);
            gl_lds16(Ub + (size_t)(n0 + r0 + lrow) * RANK + kk + cf * 8,
                     &Ulds[r0 * G2_BK]);
        }
        __syncthreads();
        #pragma unroll
        for (int ks = 0; ks < 2; ++ks) {
            bf16x8 aU[4], bT[4];
            #pragma unroll
            for (int t = 0; t < 4; ++t) {
                int ur = wx * 64 + t * 16 + l15;
                int up = (ks * 4 + quad) ^ (ur & 7);
                aU[t] = *(const bf16x8*)&Ulds[ur * G2_BK + up * 8];
                int tr = wy * 64 + t * 16 + l15;
                int tp = (ks * 4 + quad) ^ (tr & 7);
                bT[t] = *(const bf16x8*)&Tlds[tr * G2_BK + tp * 8];
            }
            #pragma unroll
            for (int nt = 0; nt < 4; ++nt)
                #pragma unroll
                for (int mt = 0; mt < 4; ++mt)
                    acc[nt][mt] = __builtin_amdgcn_mfma_f32_16x16x32_bf16(
                        aU[nt], bT[mt], acc[nt][mt], 0, 0, 0);
        }
        __syncthreads();
    }
    // epilogue: D row = outf offset (quad*4+r), col = token (l15)
    // => lane's 4 regs are 4 consecutive out-features of one row: float4 store
    float4 bv[4];
    #pragma unroll
    for (int nt = 0; nt < 4; ++nt)
        bv[nt] = *(const float4*)&bias[n0 + wx * 64 + nt * 16 + quad * 4];
    #pragma unroll
    for (int nt = 0; nt < 4; ++nt) {
        int n_base = n0 + wx * 64 + nt * 16 + quad * 4;
        #pragma unroll
        for (int mt = 0; mt < 4; ++mt) {
            int m = m0 + wy * 64 + mt * 16 + l15;
            float4 v;
            v.x = acc[nt][mt][0] + bv[nt].x;
            v.y = acc[nt][mt][1] + bv[nt].y;
            v.z = acc[nt][mt][2] + bv[nt].z;
            v.w = acc[nt][mt][3] + bv[nt].w;
            *(float4*)&out[(size_t)m * OUTF + n_base] = v;
        }
    }
}

extern "C" void kernel_launch(void* const* d_in, const int* in_sizes, int n_in,
                              void* d_out, int out_size, void* d_ws, size_t ws_size,
                              hipStream_t stream) {
    const float* x    = (const float*)d_in[0];
    const float* U    = (const float*)d_in[1];
    const float* V    = (const float*)d_in[2];
    const float* bias = (const float*)d_in[3];
    float* out = (float*)d_out;

    // ws layout: Vb (2MB) | Ub (2MB) | Tb (4MB)  => 8 MB total
    unsigned short* Vb = (unsigned short*)d_ws;
    unsigned short* Ub = Vb + (size_t)RANK * INF;
    unsigned short* Tb = Ub + (size_t)OUTF * RANK;

    cvt4<<<(RANK * INF / 4) / 256, 256, 0, stream>>>((const float4*)V, (ushort4*)Vb);
    cvt4<<<(OUTF * RANK / 4) / 256, 256, 0, stream>>>((const float4*)U, (ushort4*)Ub);
    gemm1<<<dim3(RANK / G1_BN, TOKENS / G1_BM), 512, 0, stream>>>(x, Vb, Tb);
    gemm2<<<dim3(OUTF / G2_BN, TOKENS / G2_BM), 256, 0, stream>>>(Tb, Ub, bias, out);
}